// Round 10
// baseline (449.012 us; speedup 1.0000x reference)
//
#include <hip/hip_runtime.h>

#define HW 65536
#define NOUT 81     // 9 mask + 4*18 off
#define NFEAT 192   // 144 patch + 48 passthrough
#define WROW 84     // padded weight row stride
#define OROW 96     // padded per-pixel off/mask row: mask@0..8, g-block@12+20g (+0..17)

typedef unsigned short ushort_t;

__device__ __forceinline__ float bf2f(ushort_t u) {
    union { unsigned int i; float f; } v; v.i = ((unsigned int)u) << 16; return v.f;
}
__device__ __forceinline__ ushort_t f2bf(float f) {
    union { float f; unsigned int i; } v; v.f = f;
    unsigned int r = v.i + 0x7FFF + ((v.i >> 16) & 1);   // RNE
    return (ushort_t)(r >> 16);
}

// ---------------------------------------------------------------------------
// Setup: collapse (conv3x3 -> 1x1) into a single 192->81 linear map, padded.
// ---------------------------------------------------------------------------
__global__ __launch_bounds__(256) void setup_weights(
    const float* __restrict__ off_pconv_w,  // (4,16,16,3,3)
    const float* __restrict__ off_w,        // (4,18,64)
    const float* __restrict__ off_b,        // (4,18)
    const float* __restrict__ mask_pconv_w, // (16,16,3,3)
    const float* __restrict__ mask_w,       // (9,64)
    const float* __restrict__ mask_b,       // (9,)
    float* __restrict__ WtP,                // (192,84)
    float* __restrict__ biasP)              // (81,)
{
    int id = blockIdx.x * 256 + threadIdx.x;
    const float PTS[18] = {-1,-1, -1,0, -1,1, 0,-1, 0,0, 0,1, 1,-1, 1,0, 1,1};
    if (id < NFEAT * WROW) {
        int f = id / WROW;
        int o = id % WROW;
        float v = 0.f;
        if (o < NOUT) {
            if (f < 144) {
                int p = f >> 4, c = f & 15;
                float s = 0.f;
                if (o < 9) {
                    for (int cm = 0; cm < 16; ++cm)
                        s += mask_w[o * 64 + cm] * mask_pconv_w[(cm * 16 + c) * 9 + p];
                } else {
                    int oo = o - 9, i = oo / 18, j = oo % 18;
                    for (int cm = 0; cm < 16; ++cm)
                        s += off_w[(i * 18 + j) * 64 + cm] * off_pconv_w[((i * 16 + cm) * 16 + c) * 9 + p];
                }
                v = s;
            } else {
                int c = f - 144;
                if (o < 9) v = mask_w[o * 64 + 16 + c];
                else { int oo = o - 9, i = oo / 18, j = oo % 18; v = off_w[(i * 18 + j) * 64 + 16 + c]; }
            }
        }
        WtP[id] = v;
    } else if (id < NFEAT * WROW + NOUT) {
        int o = id - NFEAT * WROW;
        float v;
        if (o < 9) v = mask_b[o];
        else {
            int oo = o - 9, i = oo / 18, j = oo % 18;
            v = off_b[i * 18 + j] + PTS[j] * (float)(2 * i + 1);
        }
        biasP[o] = v;
    }
}

// 84 FMAs: 21-output weight slice applied to 4 pixels' x values.
#define FMA21X4(X0, X1, X2, X3, WR) do {                                   \
    _Pragma("unroll")                                                      \
    for (int j5 = 0; j5 < 5; ++j5) {                                       \
        float4 w4 = *(const float4*)((WR) + 4 * j5);                       \
        acc0[4*j5+0] = fmaf(X0, w4.x, acc0[4*j5+0]);                       \
        acc0[4*j5+1] = fmaf(X0, w4.y, acc0[4*j5+1]);                       \
        acc0[4*j5+2] = fmaf(X0, w4.z, acc0[4*j5+2]);                       \
        acc0[4*j5+3] = fmaf(X0, w4.w, acc0[4*j5+3]);                       \
        acc1[4*j5+0] = fmaf(X1, w4.x, acc1[4*j5+0]);                       \
        acc1[4*j5+1] = fmaf(X1, w4.y, acc1[4*j5+1]);                       \
        acc1[4*j5+2] = fmaf(X1, w4.z, acc1[4*j5+2]);                       \
        acc1[4*j5+3] = fmaf(X1, w4.w, acc1[4*j5+3]);                       \
        acc2[4*j5+0] = fmaf(X2, w4.x, acc2[4*j5+0]);                       \
        acc2[4*j5+1] = fmaf(X2, w4.y, acc2[4*j5+1]);                       \
        acc2[4*j5+2] = fmaf(X2, w4.z, acc2[4*j5+2]);                       \
        acc2[4*j5+3] = fmaf(X2, w4.w, acc2[4*j5+3]);                       \
        acc3[4*j5+0] = fmaf(X3, w4.x, acc3[4*j5+0]);                       \
        acc3[4*j5+1] = fmaf(X3, w4.y, acc3[4*j5+1]);                       \
        acc3[4*j5+2] = fmaf(X3, w4.z, acc3[4*j5+2]);                       \
        acc3[4*j5+3] = fmaf(X3, w4.w, acc3[4*j5+3]);                       \
    }                                                                      \
    {                                                                      \
        float w20 = (WR)[20];                                              \
        acc0[20] = fmaf(X0, w20, acc0[20]);                                \
        acc1[20] = fmaf(X1, w20, acc1[20]);                                \
        acc2[20] = fmaf(X2, w20, acc2[20]);                                \
        acc3[20] = fmaf(X3, w20, acc3[20]);                                \
    }                                                                      \
} while (0)

// ---------------------------------------------------------------------------
// Conv kernel (round-9 structure): weights in LDS, 4 pixels/thread, 21-output
// slices. Stores now go to the PADDED per-pixel row layout (scalar stores).
// ---------------------------------------------------------------------------
__global__ __launch_bounds__(256, 2) void conv_px4(
    const float* __restrict__ x,     // (2,64,HW)
    const float* __restrict__ WtP,   // (192,84)
    const float* __restrict__ biasP, // (81,)
    float* __restrict__ offm)        // (2,HW,96) padded rows
{
    __shared__ float wl[NFEAT * WROW];    // 64.5 KB
    int tid = threadIdx.x;
    {
        const float4* src = (const float4*)WtP;
        float4* dst = (float4*)wl;
        for (int idx = tid; idx < NFEAT * WROW / 4; idx += 256) dst[idx] = src[idx];
    }
    __syncthreads();

    int c4 = tid & 3, grp = tid >> 2;
    int bid = blockIdx.x;            // 512
    int b = bid >> 8, h = bid & 255;
    int wbase = grp * 4;
    int pix0 = h * 256 + wbase;
    int ob0 = c4 * 20;

    float acc0[21], acc1[21], acc2[21], acc3[21];
#pragma unroll
    for (int j = 0; j < 21; ++j) {
        float bj = biasP[ob0 + j];
        acc0[j] = bj; acc1[j] = bj; acc2[j] = bj; acc3[j] = bj;
    }

    const float* xb = x + (size_t)b * 64 * HW;

#pragma unroll 1
    for (int r = 0; r < 3; ++r) {
        int hh = h + r - 1;
        bool vrow = ((unsigned)hh < 256u);
        int rbase = hh * 256 + wbase;
#pragma unroll 1
        for (int c = 0; c < 16; ++c) {
            const float* xr = xb + c * HW + rbase;
            float4 x4 = vrow ? *(const float4*)xr : make_float4(0.f, 0.f, 0.f, 0.f);
            float xm1 = (vrow && wbase > 0)       ? xr[-1] : 0.f;
            float xp4 = (vrow && wbase + 4 < 256) ? xr[4]  : 0.f;
            const float* wr0 = wl + ((r * 3 + 0) * 16 + c) * WROW + ob0;
            const float* wr1 = wl + ((r * 3 + 1) * 16 + c) * WROW + ob0;
            const float* wr2 = wl + ((r * 3 + 2) * 16 + c) * WROW + ob0;
            FMA21X4(xm1, x4.x, x4.y, x4.z, wr0);
            FMA21X4(x4.x, x4.y, x4.z, x4.w, wr1);
            FMA21X4(x4.y, x4.z, x4.w, xp4, wr2);
        }
    }
#pragma unroll 1
    for (int c = 0; c < 48; ++c) {
        float4 x4 = *(const float4*)(xb + (16 + c) * HW + pix0);
        const float* wr = wl + (144 + c) * WROW + ob0;
        FMA21X4(x4.x, x4.y, x4.z, x4.w, wr);
    }

    // scalar stores with padded-position mapping
    float* row0 = offm + ((size_t)b * HW + pix0) * OROW;
#pragma unroll
    for (int j = 0; j < 21; ++j) {
        int o = ob0 + j;
        int pos;
        if (o < 9) pos = o;
        else { int oo = o - 9; int gg = oo / 18; int rr = oo - gg * 18; pos = 12 + gg * 20 + rr; }
        row0[pos]            = acc0[j];
        row0[OROW + pos]     = acc1[j];
        row0[2 * OROW + pos] = acc2[j];
        row0[3 * OROW + pos] = acc3[j];
    }
}

// ---------------------------------------------------------------------------
// Transpose y -> t-planar Tb[(z*2+t)][pix][16c] bf16 (32B rows).
// ---------------------------------------------------------------------------
__global__ __launch_bounds__(256) void transpose_y_p(
    const float* __restrict__ y, ushort_t* __restrict__ Tb)
{
    int bid = blockIdx.x;            // 2048
    int z = bid & 7, pr = bid >> 3;
    int pix = pr * 256 + threadIdx.x;
    int xb = z >> 2, i = z & 3;

    const float* p0 = y + (size_t)(xb * 64 + i * 16) * HW + pix;
    const float* p1 = y + (size_t)((xb + 2) * 64 + i * 16) * HW + pix;

    ushort_t v[16];
#pragma unroll
    for (int c = 0; c < 16; ++c) v[c] = f2bf(p0[(size_t)c * HW]);
    uint4* d0 = (uint4*)(Tb + ((size_t)(z * 2 + 0) * HW + pix) * 16);
    d0[0] = *(const uint4*)&v[0];
    d0[1] = *(const uint4*)&v[8];

#pragma unroll
    for (int c = 0; c < 16; ++c) v[c] = f2bf(p1[(size_t)c * HW]);
    uint4* d1 = (uint4*)(Tb + ((size_t)(z * 2 + 1) * HW + pix) * 16);
    d1[0] = *(const uint4*)&v[0];
    d1[1] = *(const uint4*)&v[8];
}

// ---------------------------------------------------------------------------
// Warp kernel v6: LDS-staged tile gather.
// Block = (z, 64w x 4h tile); 512 threads = 128 pixel-quads x 4 c4 lanes x 2 pp.
// Per tensor t: stage the +-10-halo window (<=24x84 rows x 32B = 63KB) into
// LDS, then bilinear corners are ds_read_b64 (no TA line serialization).
// Out-of-window coords (>=8 sigma of the offset distribution) read global.
// ---------------------------------------------------------------------------
#define THALO 10
#define TILW 64
#define TILH 4
#define SROW 84     // fixed LDS row stride (pixels)

__global__ __launch_bounds__(512, 4) void warp_tile(
    const ushort_t* __restrict__ Tb,   // (16,HW,16) t-planar bf16
    const float* __restrict__ offm,    // (2,HW,96) padded rows
    float* __restrict__ out)           // (4,64,9,HW)
{
    __shared__ ushort_t S[24 * SROW * 16];   // 63 KB

    int bid = blockIdx.x;            // 2048 = z(8) x wt(4) x ht(64)
    int z  = bid & 7;
    int wt = (bid >> 3) & 3;
    int ht = bid >> 5;               // 0..63
    int g = z & 3, xb = z >> 2;
    int h0 = ht * TILH, w0 = wt * TILW;
    int hlo = max(h0 - THALO, 0), hhi = min(h0 + TILH - 1 + THALO, 255);
    int wlo = max(w0 - THALO, 0), whi = min(w0 + TILW - 1 + THALO, 255);
    int nh = hhi - hlo + 1, nw = whi - wlo + 1;

    int tid = threadIdx.x;
    int c4 = tid & 3, qd = tid >> 2;     // qd 0..127
    int sec = c4 * 4;                    // ushort offset in 16-ushort row

#pragma unroll
    for (int t = 0; t < 2; ++t) {
        const ushort_t* Tp = Tb + (size_t)(z * 2 + t) * HW * 16;

        __syncthreads();   // previous pass finished reading S
        // ---- stage window (coalesced 16B units along each row) ----
        int tot = nh * nw * 2;
        for (int u = tid; u < tot; u += 512) {
            int slot = u >> 1, q = u & 1;
            int ly = slot / nw, lx = slot - ly * nw;
            const uint4* src = (const uint4*)(Tp + ((size_t)((hlo + ly) * 256 + (wlo + lx))) * 16);
            *((uint4*)(S + (size_t)(ly * SROW + lx) * 16) + q) = src[q];
        }
        __syncthreads();

        // ---- process 2 pixels per thread ----
#pragma unroll 1
        for (int pp = 0; pp < 2; ++pp) {
            int lp = pp * 128 + qd;          // 0..255
            int lh = lp >> 6, lw = lp & 63;
            int h = h0 + lh, w = w0 + lw;
            int pix = h * 256 + w;

            const float* orow = offm + ((size_t)xb * HW + pix) * OROW;
            float4 m0 = *(const float4*)(orow);
            float4 m1 = *(const float4*)(orow + 4);
            float  m8 = orow[8];
            const float* obp = orow + 12 + 20 * g;   // 16B-aligned for all g
            float4 f0 = *(const float4*)(obp);
            float4 f1 = *(const float4*)(obp + 4);
            float4 f2 = *(const float4*)(obp + 8);
            float4 f3 = *(const float4*)(obp + 12);
            float2 f4 = *(const float2*)(obp + 16);
            float mk[9] = {m0.x, m0.y, m0.z, m0.w, m1.x, m1.y, m1.z, m1.w, m8};
            float of[18] = {f0.x, f0.y, f0.z, f0.w, f1.x, f1.y, f1.z, f1.w,
                            f2.x, f2.y, f2.z, f2.w, f3.x, f3.y, f3.z, f3.w,
                            f4.x, f4.y};

            float* ot = out + ((size_t)((xb + 2 * t) * 64 + g * 16 + c4 * 4)) * 9 * HW + pix;

#pragma unroll
            for (int k = 0; k < 9; ++k) {
                float m = mk[k];
                float pxf = fminf(fmaxf((float)w + of[2 * k], 0.f), 255.f);
                float pyf = fminf(fmaxf((float)h + of[2 * k + 1], 0.f), 255.f);
                float x0f = floorf(pxf), y0f = floorf(pyf);
                float wx = pxf - x0f, wy = pyf - y0f;
                int x0 = (int)x0f, y0 = (int)y0f;
                int x1 = min(x0 + 1, 255), y1 = min(y0 + 1, 255);

                float w00 = (1.f - wx) * (1.f - wy) * m;
                float w01 = wx * (1.f - wy) * m;
                float w10 = (1.f - wx) * wy * m;
                float w11 = wx * wy * m;

                bool inw = (x0 >= wlo) && (x1 <= whi) && (y0 >= hlo) && (y1 <= hhi);
                ushort4 A, B, C, D;
                if (inw) {
                    int ry0 = (y0 - hlo) * SROW - wlo;
                    int ry1 = (y1 - hlo) * SROW - wlo;
                    A = *(const ushort4*)(S + (size_t)(ry0 + x0) * 16 + sec);
                    B = *(const ushort4*)(S + (size_t)(ry0 + x1) * 16 + sec);
                    C = *(const ushort4*)(S + (size_t)(ry1 + x0) * 16 + sec);
                    D = *(const ushort4*)(S + (size_t)(ry1 + x1) * 16 + sec);
                } else {
                    A = *(const ushort4*)(Tp + (size_t)(y0 * 256 + x0) * 16 + sec);
                    B = *(const ushort4*)(Tp + (size_t)(y0 * 256 + x1) * 16 + sec);
                    C = *(const ushort4*)(Tp + (size_t)(y1 * 256 + x0) * 16 + sec);
                    D = *(const ushort4*)(Tp + (size_t)(y1 * 256 + x1) * 16 + sec);
                }

                float s0 = w00 * bf2f(A.x), s1 = w00 * bf2f(A.y);
                float s2 = w00 * bf2f(A.z), s3 = w00 * bf2f(A.w);
                s0 = fmaf(w01, bf2f(B.x), s0); s1 = fmaf(w01, bf2f(B.y), s1);
                s2 = fmaf(w01, bf2f(B.z), s2); s3 = fmaf(w01, bf2f(B.w), s3);
                s0 = fmaf(w10, bf2f(C.x), s0); s1 = fmaf(w10, bf2f(C.y), s1);
                s2 = fmaf(w10, bf2f(C.z), s2); s3 = fmaf(w10, bf2f(C.w), s3);
                s0 = fmaf(w11, bf2f(D.x), s0); s1 = fmaf(w11, bf2f(D.y), s1);
                s2 = fmaf(w11, bf2f(D.z), s2); s3 = fmaf(w11, bf2f(D.w), s3);

                float* ob = ot + (size_t)k * HW;
                ob[0]               = s0;
                ob[(size_t)9 * HW]  = s1;
                ob[(size_t)18 * HW] = s2;
                ob[(size_t)27 * HW] = s3;
            }
        }
    }
}

// ---------------------------------------------------------------------------
// Fallback path (ws too small): LDS-weight conv to planes + direct warp.
// ---------------------------------------------------------------------------
__global__ __launch_bounds__(512) void conv_offsets_lds(
    const float* __restrict__ x, const float* __restrict__ WtP,
    const float* __restrict__ biasP,
    float* __restrict__ mask_ws, float* __restrict__ off_ws)
{
    __shared__ float wl[NFEAT * WROW + NOUT];
    int tid = threadIdx.x;
    for (int idx = tid; idx < NFEAT * WROW; idx += 512) wl[idx] = WtP[idx];
    if (tid < NOUT) wl[NFEAT * WROW + tid] = biasP[tid];
    __syncthreads();

    int gid = blockIdx.x * 512 + tid;
    int b = gid >> 16;
    int pix = gid & 65535;
    int h = pix >> 8, w = pix & 255;

    float acc[NOUT];
#pragma unroll
    for (int o = 0; o < NOUT; ++o) acc[o] = wl[NFEAT * WROW + o];

    const float* xb = x + (size_t)b * 64 * HW;
    for (int p = 0; p < 9; ++p) {
        int hh = h + p / 3 - 1;
        int ww = w + p % 3 - 1;
        bool valid = ((unsigned)hh < 256u) && ((unsigned)ww < 256u);
        int poff = hh * 256 + ww;
        for (int c = 0; c < 16; ++c) {
            float xv = valid ? xb[c * HW + poff] : 0.f;
            const float* wr = &wl[(p * 16 + c) * WROW];
#pragma unroll
            for (int o = 0; o < NOUT; ++o) acc[o] = fmaf(xv, wr[o], acc[o]);
        }
    }
    for (int c = 0; c < 48; ++c) {
        float xv = xb[(16 + c) * HW + pix];
        const float* wr = &wl[(144 + c) * WROW];
#pragma unroll
        for (int o = 0; o < NOUT; ++o) acc[o] = fmaf(xv, wr[o], acc[o]);
    }
#pragma unroll
    for (int k = 0; k < 9; ++k) mask_ws[(b * 9 + k) * HW + pix] = acc[k];
#pragma unroll
    for (int t = 0; t < 72; ++t) off_ws[(b * 72 + t) * HW + pix] = acc[9 + t];
}

__global__ __launch_bounds__(256) void warp_apply(
    const float* __restrict__ y,
    const float* __restrict__ mask_ws,
    const float* __restrict__ off_ws,
    float* __restrict__ out)
{
    int w = threadIdx.x;
    int h = blockIdx.x;
    int k = blockIdx.y;
    int z = blockIdx.z;
    int xb = z >> 2, i = z & 3;
    int pix = h * 256 + w;

    float ox = off_ws[(size_t)(z * 18 + 2 * k) * HW + pix];
    float oy = off_ws[(size_t)(z * 18 + 2 * k + 1) * HW + pix];
    float m  = mask_ws[(size_t)(xb * 9 + k) * HW + pix];

    float px = fminf(fmaxf((float)w + ox, 0.f), 255.f);
    float py = fminf(fmaxf((float)h + oy, 0.f), 255.f);
    float x0f = floorf(px), y0f = floorf(py);
    float wx = px - x0f, wy = py - y0f;
    int x0 = (int)x0f, y0 = (int)y0f;
    int x1 = min(x0 + 1, 255), y1 = min(y0 + 1, 255);

    float w00 = (1.f - wx) * (1.f - wy) * m;
    float w01 = wx * (1.f - wy) * m;
    float w10 = (1.f - wx) * wy * m;
    float w11 = wx * wy * m;

    int o00 = y0 * 256 + x0, o01 = y0 * 256 + x1;
    int o10 = y1 * 256 + x0, o11 = y1 * 256 + x1;

    const float* p1 = y + (size_t)(xb * 64 + i * 16) * HW;
    const float* p2 = y + (size_t)((xb + 2) * 64 + i * 16) * HW;
    float* out1 = out + ((size_t)(xb * 64 + i * 16) * 9 + k) * HW + pix;
    float* out2 = out + ((size_t)((xb + 2) * 64 + i * 16) * 9 + k) * HW + pix;

#pragma unroll
    for (int c = 0; c < 16; ++c) {
        const float* q = p1 + (size_t)c * HW;
        float v = w00 * q[o00] + w01 * q[o01] + w10 * q[o10] + w11 * q[o11];
        out1[(size_t)c * 9 * HW] = v;
        q = p2 + (size_t)c * HW;
        v = w00 * q[o00] + w01 * q[o01] + w10 * q[o10] + w11 * q[o11];
        out2[(size_t)c * 9 * HW] = v;
    }
}

// ---------------------------------------------------------------------------
extern "C" void kernel_launch(void* const* d_in, const int* in_sizes, int n_in,
                              void* d_out, int out_size, void* d_ws, size_t ws_size,
                              hipStream_t stream) {
    const float* x            = (const float*)d_in[0];
    const float* y            = (const float*)d_in[1];
    const float* off_pconv_w  = (const float*)d_in[2];
    const float* off_w        = (const float*)d_in[3];
    const float* off_b        = (const float*)d_in[4];
    const float* mask_pconv_w = (const float*)d_in[5];
    const float* mask_w       = (const float*)d_in[6];
    const float* mask_b       = (const float*)d_in[7];
    float* out = (float*)d_out;

    // ws: [WtP 192*84 f32 | biasP : 64KB] [offm (2,HW,96) f32: 48MB]
    //     [Tb (16,HW,16) bf16: 33.6MB]
    float* WtP     = (float*)d_ws;
    float* biasP   = WtP + NFEAT * WROW;
    float* offm    = (float*)((char*)d_ws + 65536);
    ushort_t* Tb   = (ushort_t*)((char*)offm + (size_t)2 * HW * OROW * 4);
    size_t need = 65536 + (size_t)2 * HW * OROW * 4 + (size_t)16 * HW * 16 * 2;

    setup_weights<<<64, 256, 0, stream>>>(off_pconv_w, off_w, off_b,
                                          mask_pconv_w, mask_w, mask_b, WtP, biasP);

    if (ws_size >= need) {
        conv_px4<<<512, 256, 0, stream>>>(x, WtP, biasP, offm);
        transpose_y_p<<<2048, 256, 0, stream>>>(y, Tb);
        warp_tile<<<2048, 512, 0, stream>>>(Tb, offm, out);
    } else {
        float* mask_ws = (float*)((char*)d_ws + 131072);
        float* off_ws  = mask_ws + (size_t)2 * 9 * HW;
        conv_offsets_lds<<<256, 512, 0, stream>>>(x, WtP, biasP, mask_ws, off_ws);
        dim3 g2(256, 9, 8);
        warp_apply<<<g2, 256, 0, stream>>>(y, mask_ws, off_ws, out);
    }
}

// Round 11
// 387.317 us; speedup vs baseline: 1.1593x; 1.1593x over previous
//
#include <hip/hip_runtime.h>

#define HW 65536
#define NOUT 81     // 9 mask + 4*18 off
#define NFEAT 192   // 144 patch + 48 passthrough
#define WROW 84     // padded weight row stride

typedef unsigned short ushort_t;

__device__ __forceinline__ float bf2f(ushort_t u) {
    union { unsigned int i; float f; } v; v.i = ((unsigned int)u) << 16; return v.f;
}
__device__ __forceinline__ ushort_t f2bf(float f) {
    union { float f; unsigned int i; } v; v.f = f;
    unsigned int r = v.i + 0x7FFF + ((v.i >> 16) & 1);   // RNE
    return (ushort_t)(r >> 16);
}

// ---------------------------------------------------------------------------
// Setup: collapse (conv3x3 -> 1x1) into a single 192->81 linear map, padded
// to (192,84) rows so 21-wide lane slices are float4-aligned.
// ---------------------------------------------------------------------------
__global__ __launch_bounds__(256) void setup_weights(
    const float* __restrict__ off_pconv_w,  // (4,16,16,3,3)
    const float* __restrict__ off_w,        // (4,18,64)
    const float* __restrict__ off_b,        // (4,18)
    const float* __restrict__ mask_pconv_w, // (16,16,3,3)
    const float* __restrict__ mask_w,       // (9,64)
    const float* __restrict__ mask_b,       // (9,)
    float* __restrict__ WtP,                // (192,84)
    float* __restrict__ biasP)              // (81,)
{
    int id = blockIdx.x * 256 + threadIdx.x;
    const float PTS[18] = {-1,-1, -1,0, -1,1, 0,-1, 0,0, 0,1, 1,-1, 1,0, 1,1};
    if (id < NFEAT * WROW) {
        int f = id / WROW;
        int o = id % WROW;
        float v = 0.f;
        if (o < NOUT) {
            if (f < 144) {
                int p = f >> 4, c = f & 15;
                float s = 0.f;
                if (o < 9) {
                    for (int cm = 0; cm < 16; ++cm)
                        s += mask_w[o * 64 + cm] * mask_pconv_w[(cm * 16 + c) * 9 + p];
                } else {
                    int oo = o - 9, i = oo / 18, j = oo % 18;
                    for (int cm = 0; cm < 16; ++cm)
                        s += off_w[(i * 18 + j) * 64 + cm] * off_pconv_w[((i * 16 + cm) * 16 + c) * 9 + p];
                }
                v = s;
            } else {
                int c = f - 144;
                if (o < 9) v = mask_w[o * 64 + 16 + c];
                else { int oo = o - 9, i = oo / 18, j = oo % 18; v = off_w[(i * 18 + j) * 64 + 16 + c]; }
            }
        }
        WtP[id] = v;
    } else if (id < NFEAT * WROW + NOUT) {
        int o = id - NFEAT * WROW;
        float v;
        if (o < 9) v = mask_b[o];
        else {
            int oo = o - 9, i = oo / 18, j = oo % 18;
            v = off_b[i * 18 + j] + PTS[j] * (float)(2 * i + 1);
        }
        biasP[o] = v;
    }
}

// 84 FMAs: 21-output weight slice applied to 4 pixels' x values.
#define FMA21X4(X0, X1, X2, X3, WR) do {                                   \
    _Pragma("unroll")                                                      \
    for (int j5 = 0; j5 < 5; ++j5) {                                       \
        float4 w4 = *(const float4*)((WR) + 4 * j5);                       \
        acc0[4*j5+0] = fmaf(X0, w4.x, acc0[4*j5+0]);                       \
        acc0[4*j5+1] = fmaf(X0, w4.y, acc0[4*j5+1]);                       \
        acc0[4*j5+2] = fmaf(X0, w4.z, acc0[4*j5+2]);                       \
        acc0[4*j5+3] = fmaf(X0, w4.w, acc0[4*j5+3]);                       \
        acc1[4*j5+0] = fmaf(X1, w4.x, acc1[4*j5+0]);                       \
        acc1[4*j5+1] = fmaf(X1, w4.y, acc1[4*j5+1]);                       \
        acc1[4*j5+2] = fmaf(X1, w4.z, acc1[4*j5+2]);                       \
        acc1[4*j5+3] = fmaf(X1, w4.w, acc1[4*j5+3]);                       \
        acc2[4*j5+0] = fmaf(X2, w4.x, acc2[4*j5+0]);                       \
        acc2[4*j5+1] = fmaf(X2, w4.y, acc2[4*j5+1]);                       \
        acc2[4*j5+2] = fmaf(X2, w4.z, acc2[4*j5+2]);                       \
        acc2[4*j5+3] = fmaf(X2, w4.w, acc2[4*j5+3]);                       \
        acc3[4*j5+0] = fmaf(X3, w4.x, acc3[4*j5+0]);                       \
        acc3[4*j5+1] = fmaf(X3, w4.y, acc3[4*j5+1]);                       \
        acc3[4*j5+2] = fmaf(X3, w4.z, acc3[4*j5+2]);                       \
        acc3[4*j5+3] = fmaf(X3, w4.w, acc3[4*j5+3]);                       \
    }                                                                      \
    {                                                                      \
        float w20 = (WR)[20];                                              \
        acc0[20] = fmaf(X0, w20, acc0[20]);                                \
        acc1[20] = fmaf(X1, w20, acc1[20]);                                \
        acc2[20] = fmaf(X2, w20, acc2[20]);                                \
        acc3[20] = fmaf(X3, w20, acc3[20]);                                \
    }                                                                      \
} while (0)

// ---------------------------------------------------------------------------
// Conv: 4 pixels/thread, 21-output lane slices, weights in LDS read as
// float4 (6 LDS instrs per 84 FMAs vs 81 b32 reads per 81 FMAs in the old
// version). Writes the PLANE layout (mask (2,9,HW), off (2,72,HW)) that
// warp_b consumes. Overlap outputs (o=20/40/60) are written by two lanes
// with bit-identical values.
// ---------------------------------------------------------------------------
__global__ __launch_bounds__(256, 2) void conv_px4(
    const float* __restrict__ x,     // (2,64,HW)
    const float* __restrict__ WtP,   // (192,84)
    const float* __restrict__ biasP, // (81,)
    float* __restrict__ mask_ws,     // (2,9,HW)
    float* __restrict__ off_ws)      // (2,72,HW)
{
    __shared__ float wl[NFEAT * WROW];    // 64.5 KB
    int tid = threadIdx.x;
    {
        const float4* src = (const float4*)WtP;
        float4* dst = (float4*)wl;
        for (int idx = tid; idx < NFEAT * WROW / 4; idx += 256) dst[idx] = src[idx];
    }
    __syncthreads();

    int c4 = tid & 3, grp = tid >> 2;
    int bid = blockIdx.x;            // 512
    int b = bid >> 8, h = bid & 255;
    int wbase = grp * 4;
    int pix0 = h * 256 + wbase;
    int ob0 = c4 * 20;

    float acc0[21], acc1[21], acc2[21], acc3[21];
#pragma unroll
    for (int j = 0; j < 21; ++j) {
        float bj = biasP[ob0 + j];
        acc0[j] = bj; acc1[j] = bj; acc2[j] = bj; acc3[j] = bj;
    }

    const float* xb = x + (size_t)b * 64 * HW;

    // 3x3 patch over channels 0..15: row-window of 6 values serves all 3 dw.
#pragma unroll 1
    for (int r = 0; r < 3; ++r) {
        int hh = h + r - 1;
        bool vrow = ((unsigned)hh < 256u);
        int rbase = hh * 256 + wbase;
#pragma unroll 1
        for (int c = 0; c < 16; ++c) {
            const float* xr = xb + c * HW + rbase;
            float4 x4 = vrow ? *(const float4*)xr : make_float4(0.f, 0.f, 0.f, 0.f);
            float xm1 = (vrow && wbase > 0)       ? xr[-1] : 0.f;
            float xp4 = (vrow && wbase + 4 < 256) ? xr[4]  : 0.f;
            const float* wr0 = wl + ((r * 3 + 0) * 16 + c) * WROW + ob0;
            const float* wr1 = wl + ((r * 3 + 1) * 16 + c) * WROW + ob0;
            const float* wr2 = wl + ((r * 3 + 2) * 16 + c) * WROW + ob0;
            FMA21X4(xm1, x4.x, x4.y, x4.z, wr0);   // dw=-1
            FMA21X4(x4.x, x4.y, x4.z, x4.w, wr1);  // dw= 0
            FMA21X4(x4.y, x4.z, x4.w, xp4, wr2);   // dw=+1
        }
    }
#pragma unroll 1
    for (int c = 0; c < 48; ++c) {
        float4 x4 = *(const float4*)(xb + (16 + c) * HW + pix0);
        const float* wr = wl + (144 + c) * WROW + ob0;
        FMA21X4(x4.x, x4.y, x4.z, x4.w, wr);
    }

    // plane-layout stores: 4 consecutive pixels per output index
#pragma unroll
    for (int j = 0; j < 21; ++j) {
        int o = ob0 + j;
        float* pl;
        if (o < 9) pl = mask_ws + (size_t)(b * 9 + o) * HW + pix0;
        else       pl = off_ws  + (size_t)(b * 72 + (o - 9)) * HW + pix0;
        pl[0] = acc0[j];
        pl[1] = acc1[j];
        pl[2] = acc2[j];
        pl[3] = acc3[j];
    }
}

// ---------------------------------------------------------------------------
// Transpose y (4,64,HW) f32 -> Tb[(t*8+z)][pix][16c] bf16 (32B rows).
// (verbatim round 6)
// ---------------------------------------------------------------------------
__global__ __launch_bounds__(256) void transpose_y_b(
    const float* __restrict__ y, ushort_t* __restrict__ Tb)
{
    int bid = blockIdx.x;            // 2048
    int z = bid & 7, pr = bid >> 3;
    int pix = pr * 256 + threadIdx.x;
    int xb = z >> 2, i = z & 3;

    const float* p1 = y + (size_t)(xb * 64 + i * 16) * HW + pix;
    const float* p2 = y + (size_t)((xb + 2) * 64 + i * 16) * HW + pix;

    ushort_t v[16];
#pragma unroll
    for (int c = 0; c < 16; ++c) v[c] = f2bf(p1[(size_t)c * HW]);
    uint4* dst = (uint4*)(Tb + ((size_t)z * HW + pix) * 16);
    dst[0] = *(const uint4*)&v[0];
    dst[1] = *(const uint4*)&v[8];

#pragma unroll
    for (int c = 0; c < 16; ++c) v[c] = f2bf(p2[(size_t)c * HW]);
    dst = (uint4*)(Tb + ((size_t)(8 + z) * HW + pix) * 16);
    dst[0] = *(const uint4*)&v[0];
    dst[1] = *(const uint4*)&v[8];
}

// ---------------------------------------------------------------------------
// Warp kernel (verbatim round 6 warp_b, the best measured: ~266 us).
// ---------------------------------------------------------------------------
__global__ __launch_bounds__(256) void warp_apply_b(
    const ushort_t* __restrict__ Tb,    // (16,HW,16) bf16
    const float* __restrict__ mask_ws,  // (2,9,HW)
    const float* __restrict__ off_ws,   // (2,72,HW)
    float* __restrict__ out)            // (4,64,9,256,256)
{
    int bid = blockIdx.x;            // 16384
    int z  = bid & 7;
    int wc = (bid >> 3) & 3;
    int h  = (bid >> 5) & 255;
    int t  = bid >> 13;
    int c4 = threadIdx.x & 3;
    int pl = threadIdx.x >> 2;       // 0..63
    int w  = wc * 64 + pl;
    int pix = h * 256 + w;
    int xb = z >> 2, i = z & 3;

    const ushort_t* Tt = Tb + (size_t)(t * 8 + z) * HW * 16;

    float oxv[9], oyv[9], mv[9];
#pragma unroll
    for (int k = 0; k < 9; ++k) {
        oxv[k] = off_ws[(size_t)(z * 18 + 2 * k) * HW + pix];
        oyv[k] = off_ws[(size_t)(z * 18 + 2 * k + 1) * HW + pix];
        mv[k]  = mask_ws[(size_t)(xb * 9 + k) * HW + pix];
    }

    float* obase = out + ((size_t)((xb + 2 * t) * 64 + i * 16 + c4 * 4)) * 9 * HW + pix;
    int sec = c4 * 4;

#pragma unroll 1
    for (int k = 0; k < 9; ++k) {
        float m = mv[k];
        float px = fminf(fmaxf((float)w + oxv[k], 0.f), 255.f);
        float py = fminf(fmaxf((float)h + oyv[k], 0.f), 255.f);
        float x0f = floorf(px), y0f = floorf(py);
        float wx = px - x0f, wy = py - y0f;
        int x0 = (int)x0f, y0 = (int)y0f;
        int x1 = min(x0 + 1, 255), y1 = min(y0 + 1, 255);

        float w00 = (1.f - wx) * (1.f - wy) * m;
        float w01 = wx * (1.f - wy) * m;
        float w10 = (1.f - wx) * wy * m;
        float w11 = wx * wy * m;

        ushort4 va = *(const ushort4*)(Tt + (size_t)(y0 * 256 + x0) * 16 + sec);
        ushort4 vb = *(const ushort4*)(Tt + (size_t)(y0 * 256 + x1) * 16 + sec);
        ushort4 vc = *(const ushort4*)(Tt + (size_t)(y1 * 256 + x0) * 16 + sec);
        ushort4 vd = *(const ushort4*)(Tt + (size_t)(y1 * 256 + x1) * 16 + sec);

        float a0 = w00 * bf2f(va.x), a1 = w00 * bf2f(va.y);
        float a2 = w00 * bf2f(va.z), a3 = w00 * bf2f(va.w);
        a0 = fmaf(w01, bf2f(vb.x), a0); a1 = fmaf(w01, bf2f(vb.y), a1);
        a2 = fmaf(w01, bf2f(vb.z), a2); a3 = fmaf(w01, bf2f(vb.w), a3);
        a0 = fmaf(w10, bf2f(vc.x), a0); a1 = fmaf(w10, bf2f(vc.y), a1);
        a2 = fmaf(w10, bf2f(vc.z), a2); a3 = fmaf(w10, bf2f(vc.w), a3);
        a0 = fmaf(w11, bf2f(vd.x), a0); a1 = fmaf(w11, bf2f(vd.y), a1);
        a2 = fmaf(w11, bf2f(vd.z), a2); a3 = fmaf(w11, bf2f(vd.w), a3);

        float* ob = obase + (size_t)k * HW;
        ob[0]                  = a0;
        ob[(size_t)9 * HW]     = a1;
        ob[(size_t)18 * HW]    = a2;
        ob[(size_t)27 * HW]    = a3;
    }
}

// ---------------------------------------------------------------------------
// Fallback path (ws too small): LDS-weight conv to planes + direct warp.
// ---------------------------------------------------------------------------
__global__ __launch_bounds__(512) void conv_offsets_lds(
    const float* __restrict__ x, const float* __restrict__ WtP,
    const float* __restrict__ biasP,
    float* __restrict__ mask_ws, float* __restrict__ off_ws)
{
    __shared__ float wl[NFEAT * WROW + NOUT];
    int tid = threadIdx.x;
    for (int idx = tid; idx < NFEAT * WROW; idx += 512) wl[idx] = WtP[idx];
    if (tid < NOUT) wl[NFEAT * WROW + tid] = biasP[tid];
    __syncthreads();

    int gid = blockIdx.x * 512 + tid;
    int b = gid >> 16;
    int pix = gid & 65535;
    int h = pix >> 8, w = pix & 255;

    float acc[NOUT];
#pragma unroll
    for (int o = 0; o < NOUT; ++o) acc[o] = wl[NFEAT * WROW + o];

    const float* xb = x + (size_t)b * 64 * HW;
    for (int p = 0; p < 9; ++p) {
        int hh = h + p / 3 - 1;
        int ww = w + p % 3 - 1;
        bool valid = ((unsigned)hh < 256u) && ((unsigned)ww < 256u);
        int poff = hh * 256 + ww;
        for (int c = 0; c < 16; ++c) {
            float xv = valid ? xb[c * HW + poff] : 0.f;
            const float* wr = &wl[(p * 16 + c) * WROW];
#pragma unroll
            for (int o = 0; o < NOUT; ++o) acc[o] = fmaf(xv, wr[o], acc[o]);
        }
    }
    for (int c = 0; c < 48; ++c) {
        float xv = xb[(16 + c) * HW + pix];
        const float* wr = &wl[(144 + c) * WROW];
#pragma unroll
        for (int o = 0; o < NOUT; ++o) acc[o] = fmaf(xv, wr[o], acc[o]);
    }
#pragma unroll
    for (int k = 0; k < 9; ++k) mask_ws[(b * 9 + k) * HW + pix] = acc[k];
#pragma unroll
    for (int t = 0; t < 72; ++t) off_ws[(b * 72 + t) * HW + pix] = acc[9 + t];
}

__global__ __launch_bounds__(256) void warp_apply(
    const float* __restrict__ y,
    const float* __restrict__ mask_ws,
    const float* __restrict__ off_ws,
    float* __restrict__ out)
{
    int w = threadIdx.x;
    int h = blockIdx.x;
    int k = blockIdx.y;
    int z = blockIdx.z;
    int xb = z >> 2, i = z & 3;
    int pix = h * 256 + w;

    float ox = off_ws[(size_t)(z * 18 + 2 * k) * HW + pix];
    float oy = off_ws[(size_t)(z * 18 + 2 * k + 1) * HW + pix];
    float m  = mask_ws[(size_t)(xb * 9 + k) * HW + pix];

    float px = fminf(fmaxf((float)w + ox, 0.f), 255.f);
    float py = fminf(fmaxf((float)h + oy, 0.f), 255.f);
    float x0f = floorf(px), y0f = floorf(py);
    float wx = px - x0f, wy = py - y0f;
    int x0 = (int)x0f, y0 = (int)y0f;
    int x1 = min(x0 + 1, 255), y1 = min(y0 + 1, 255);

    float w00 = (1.f - wx) * (1.f - wy) * m;
    float w01 = wx * (1.f - wy) * m;
    float w10 = (1.f - wx) * wy * m;
    float w11 = wx * wy * m;

    int o00 = y0 * 256 + x0, o01 = y0 * 256 + x1;
    int o10 = y1 * 256 + x0, o11 = y1 * 256 + x1;

    const float* p1 = y + (size_t)(xb * 64 + i * 16) * HW;
    const float* p2 = y + (size_t)((xb + 2) * 64 + i * 16) * HW;
    float* out1 = out + ((size_t)(xb * 64 + i * 16) * 9 + k) * HW + pix;
    float* out2 = out + ((size_t)((xb + 2) * 64 + i * 16) * 9 + k) * HW + pix;

#pragma unroll
    for (int c = 0; c < 16; ++c) {
        const float* q = p1 + (size_t)c * HW;
        float v = w00 * q[o00] + w01 * q[o01] + w10 * q[o10] + w11 * q[o11];
        out1[(size_t)c * 9 * HW] = v;
        q = p2 + (size_t)c * HW;
        v = w00 * q[o00] + w01 * q[o01] + w10 * q[o10] + w11 * q[o11];
        out2[(size_t)c * 9 * HW] = v;
    }
}

// ---------------------------------------------------------------------------
extern "C" void kernel_launch(void* const* d_in, const int* in_sizes, int n_in,
                              void* d_out, int out_size, void* d_ws, size_t ws_size,
                              hipStream_t stream) {
    const float* x            = (const float*)d_in[0];
    const float* y            = (const float*)d_in[1];
    const float* off_pconv_w  = (const float*)d_in[2];
    const float* off_w        = (const float*)d_in[3];
    const float* off_b        = (const float*)d_in[4];
    const float* mask_pconv_w = (const float*)d_in[5];
    const float* mask_w       = (const float*)d_in[6];
    const float* mask_b       = (const float*)d_in[7];
    float* out = (float*)d_out;

    // ws: [WtP 192*84 f32 + biasP: 64KB] [mask (2,9,HW) f32: 4.7MB]
    //     [off (2,72,HW) f32: 37.7MB] [Tb (16,HW,16) bf16: 33.6MB]  ~76MB
    float* WtP     = (float*)d_ws;
    float* biasP   = WtP + NFEAT * WROW;
    float* mask_ws = (float*)((char*)d_ws + 65536);
    float* off_ws  = mask_ws + (size_t)2 * 9 * HW;
    ushort_t* Tb   = (ushort_t*)(off_ws + (size_t)2 * 72 * HW);
    size_t need = 65536 + (size_t)2 * 9 * HW * 4 + (size_t)2 * 72 * HW * 4
                + (size_t)16 * HW * 16 * 2;

    setup_weights<<<64, 256, 0, stream>>>(off_pconv_w, off_w, off_b,
                                          mask_pconv_w, mask_w, mask_b, WtP, biasP);

    if (ws_size >= need) {
        conv_px4<<<512, 256, 0, stream>>>(x, WtP, biasP, mask_ws, off_ws);
        transpose_y_b<<<2048, 256, 0, stream>>>(y, Tb);
        warp_apply_b<<<16384, 256, 0, stream>>>(Tb, mask_ws, off_ws, out);
    } else {
        conv_offsets_lds<<<256, 512, 0, stream>>>(x, WtP, biasP, mask_ws, off_ws);
        dim3 g2(256, 9, 8);
        warp_apply<<<g2, 256, 0, stream>>>(y, mask_ws, off_ws, out);
    }
}

// Round 12
// 299.565 us; speedup vs baseline: 1.4989x; 1.2929x over previous
//
#include <hip/hip_runtime.h>

#define HW 65536
#define NOUT 81     // 9 mask + 4*18 off
#define NFEAT 192   // 144 patch + 48 passthrough
#define WROW 84     // padded weight row stride

typedef unsigned short ushort_t;
typedef unsigned int uint_t;

__device__ __forceinline__ float bf2f(ushort_t u) {
    union { unsigned int i; float f; } v; v.i = ((unsigned int)u) << 16; return v.f;
}
__device__ __forceinline__ float bfhi(uint_t u) {   // high ushort IS the f32 pattern
    union { unsigned int i; float f; } v; v.i = u & 0xffff0000u; return v.f;
}
__device__ __forceinline__ float bflo(uint_t u) {
    union { unsigned int i; float f; } v; v.i = u << 16; return v.f;
}
__device__ __forceinline__ ushort_t f2bf(float f) {
    union { float f; unsigned int i; } v; v.f = f;
    unsigned int r = v.i + 0x7FFF + ((v.i >> 16) & 1);   // RNE
    return (ushort_t)(r >> 16);
}

// ---------------------------------------------------------------------------
// Setup: collapse (conv3x3 -> 1x1) into a single 192->81 linear map, padded.
// ---------------------------------------------------------------------------
__global__ __launch_bounds__(256) void setup_weights(
    const float* __restrict__ off_pconv_w,  // (4,16,16,3,3)
    const float* __restrict__ off_w,        // (4,18,64)
    const float* __restrict__ off_b,        // (4,18)
    const float* __restrict__ mask_pconv_w, // (16,16,3,3)
    const float* __restrict__ mask_w,       // (9,64)
    const float* __restrict__ mask_b,       // (9,)
    float* __restrict__ WtP,                // (192,84)
    float* __restrict__ biasP)              // (81,)
{
    int id = blockIdx.x * 256 + threadIdx.x;
    const float PTS[18] = {-1,-1, -1,0, -1,1, 0,-1, 0,0, 0,1, 1,-1, 1,0, 1,1};
    if (id < NFEAT * WROW) {
        int f = id / WROW;
        int o = id % WROW;
        float v = 0.f;
        if (o < NOUT) {
            if (f < 144) {
                int p = f >> 4, c = f & 15;
                float s = 0.f;
                if (o < 9) {
                    for (int cm = 0; cm < 16; ++cm)
                        s += mask_w[o * 64 + cm] * mask_pconv_w[(cm * 16 + c) * 9 + p];
                } else {
                    int oo = o - 9, i = oo / 18, j = oo % 18;
                    for (int cm = 0; cm < 16; ++cm)
                        s += off_w[(i * 18 + j) * 64 + cm] * off_pconv_w[((i * 16 + cm) * 16 + c) * 9 + p];
                }
                v = s;
            } else {
                int c = f - 144;
                if (o < 9) v = mask_w[o * 64 + 16 + c];
                else { int oo = o - 9, i = oo / 18, j = oo % 18; v = off_w[(i * 18 + j) * 64 + 16 + c]; }
            }
        }
        WtP[id] = v;
    } else if (id < NFEAT * WROW + NOUT) {
        int o = id - NFEAT * WROW;
        float v;
        if (o < 9) v = mask_b[o];
        else {
            int oo = o - 9, i = oo / 18, j = oo % 18;
            v = off_b[i * 18 + j] + PTS[j] * (float)(2 * i + 1);
        }
        biasP[o] = v;
    }
}

// 84 FMAs: 21-output weight slice applied to 4 pixels' x values.
#define FMA21X4(X0, X1, X2, X3, WR) do {                                   \
    _Pragma("unroll")                                                      \
    for (int j5 = 0; j5 < 5; ++j5) {                                       \
        float4 w4 = *(const float4*)((WR) + 4 * j5);                       \
        acc0[4*j5+0] = fmaf(X0, w4.x, acc0[4*j5+0]);                       \
        acc0[4*j5+1] = fmaf(X0, w4.y, acc0[4*j5+1]);                       \
        acc0[4*j5+2] = fmaf(X0, w4.z, acc0[4*j5+2]);                       \
        acc0[4*j5+3] = fmaf(X0, w4.w, acc0[4*j5+3]);                       \
        acc1[4*j5+0] = fmaf(X1, w4.x, acc1[4*j5+0]);                       \
        acc1[4*j5+1] = fmaf(X1, w4.y, acc1[4*j5+1]);                       \
        acc1[4*j5+2] = fmaf(X1, w4.z, acc1[4*j5+2]);                       \
        acc1[4*j5+3] = fmaf(X1, w4.w, acc1[4*j5+3]);                       \
        acc2[4*j5+0] = fmaf(X2, w4.x, acc2[4*j5+0]);                       \
        acc2[4*j5+1] = fmaf(X2, w4.y, acc2[4*j5+1]);                       \
        acc2[4*j5+2] = fmaf(X2, w4.z, acc2[4*j5+2]);                       \
        acc2[4*j5+3] = fmaf(X2, w4.w, acc2[4*j5+3]);                       \
        acc3[4*j5+0] = fmaf(X3, w4.x, acc3[4*j5+0]);                       \
        acc3[4*j5+1] = fmaf(X3, w4.y, acc3[4*j5+1]);                       \
        acc3[4*j5+2] = fmaf(X3, w4.z, acc3[4*j5+2]);                       \
        acc3[4*j5+3] = fmaf(X3, w4.w, acc3[4*j5+3]);                       \
    }                                                                      \
    {                                                                      \
        float w20 = (WR)[20];                                              \
        acc0[20] = fmaf(X0, w20, acc0[20]);                                \
        acc1[20] = fmaf(X1, w20, acc1[20]);                                \
        acc2[20] = fmaf(X2, w20, acc2[20]);                                \
        acc3[20] = fmaf(X3, w20, acc3[20]);                                \
    }                                                                      \
} while (0)

// ---------------------------------------------------------------------------
// Conv (round-11, unchanged): 4 px/thread, float4 LDS weight reads, plane out.
// ---------------------------------------------------------------------------
__global__ __launch_bounds__(256, 2) void conv_px4(
    const float* __restrict__ x,     // (2,64,HW)
    const float* __restrict__ WtP,   // (192,84)
    const float* __restrict__ biasP, // (81,)
    float* __restrict__ mask_ws,     // (2,9,HW)
    float* __restrict__ off_ws)      // (2,72,HW)
{
    __shared__ float wl[NFEAT * WROW];    // 64.5 KB
    int tid = threadIdx.x;
    {
        const float4* src = (const float4*)WtP;
        float4* dst = (float4*)wl;
        for (int idx = tid; idx < NFEAT * WROW / 4; idx += 256) dst[idx] = src[idx];
    }
    __syncthreads();

    int c4 = tid & 3, grp = tid >> 2;
    int bid = blockIdx.x;            // 512
    int b = bid >> 8, h = bid & 255;
    int wbase = grp * 4;
    int pix0 = h * 256 + wbase;
    int ob0 = c4 * 20;

    float acc0[21], acc1[21], acc2[21], acc3[21];
#pragma unroll
    for (int j = 0; j < 21; ++j) {
        float bj = biasP[ob0 + j];
        acc0[j] = bj; acc1[j] = bj; acc2[j] = bj; acc3[j] = bj;
    }

    const float* xb = x + (size_t)b * 64 * HW;

#pragma unroll 1
    for (int r = 0; r < 3; ++r) {
        int hh = h + r - 1;
        bool vrow = ((unsigned)hh < 256u);
        int rbase = hh * 256 + wbase;
#pragma unroll 1
        for (int c = 0; c < 16; ++c) {
            const float* xr = xb + c * HW + rbase;
            float4 x4 = vrow ? *(const float4*)xr : make_float4(0.f, 0.f, 0.f, 0.f);
            float xm1 = (vrow && wbase > 0)       ? xr[-1] : 0.f;
            float xp4 = (vrow && wbase + 4 < 256) ? xr[4]  : 0.f;
            const float* wr0 = wl + ((r * 3 + 0) * 16 + c) * WROW + ob0;
            const float* wr1 = wl + ((r * 3 + 1) * 16 + c) * WROW + ob0;
            const float* wr2 = wl + ((r * 3 + 2) * 16 + c) * WROW + ob0;
            FMA21X4(xm1, x4.x, x4.y, x4.z, wr0);
            FMA21X4(x4.x, x4.y, x4.z, x4.w, wr1);
            FMA21X4(x4.y, x4.z, x4.w, xp4, wr2);
        }
    }
#pragma unroll 1
    for (int c = 0; c < 48; ++c) {
        float4 x4 = *(const float4*)(xb + (16 + c) * HW + pix0);
        const float* wr = wl + (144 + c) * WROW + ob0;
        FMA21X4(x4.x, x4.y, x4.z, x4.w, wr);
    }

#pragma unroll
    for (int j = 0; j < 21; ++j) {
        int o = ob0 + j;
        float* pl;
        if (o < 9) pl = mask_ws + (size_t)(b * 9 + o) * HW + pix0;
        else       pl = off_ws  + (size_t)(b * 72 + (o - 9)) * HW + pix0;
        pl[0] = acc0[j];
        pl[1] = acc1[j];
        pl[2] = acc2[j];
        pl[3] = acc3[j];
    }
}

// ---------------------------------------------------------------------------
// Transpose y -> c4-major interleaved Tc[z][pix][c4:{t0 4ch, t1 4ch}] bf16.
// Row = 64B; a thread's (c4) slice of BOTH tensors is one 16B uint4.
// ---------------------------------------------------------------------------
__global__ __launch_bounds__(256) void transpose_y_c(
    const float* __restrict__ y, ushort_t* __restrict__ Tc)
{
    int bid = blockIdx.x;            // 2048
    int z = bid & 7, pr = bid >> 3;
    int pix = pr * 256 + threadIdx.x;
    int xb = z >> 2, i = z & 3;

    const float* p0 = y + (size_t)(xb * 64 + i * 16) * HW + pix;
    const float* p1 = y + (size_t)((xb + 2) * 64 + i * 16) * HW + pix;

    ushort_t v0[16], v1[16];
#pragma unroll
    for (int c = 0; c < 16; ++c) v0[c] = f2bf(p0[(size_t)c * HW]);
#pragma unroll
    for (int c = 0; c < 16; ++c) v1[c] = f2bf(p1[(size_t)c * HW]);

    uint4* dst = (uint4*)(Tc + ((size_t)z * HW + pix) * 32);
#pragma unroll
    for (int j = 0; j < 4; ++j) {
        ushort_t row[8] = {v0[4*j], v0[4*j+1], v0[4*j+2], v0[4*j+3],
                           v1[4*j], v1[4*j+1], v1[4*j+2], v1[4*j+3]};
        dst[j] = *(const uint4*)row;
    }
}

// ---------------------------------------------------------------------------
// Warp kernel v7: one thread = (pixel, c4), BOTH tensors. Per k: 4 uint4
// gathers (each covers 4ch x 2 tensors) + 8 nontemporal stores. Gather VMEM
// instr count halved vs v5; off/mask hoist loads halved (t merged).
// ---------------------------------------------------------------------------
__global__ __launch_bounds__(256) void warp_apply_c(
    const ushort_t* __restrict__ Tc,    // (8,HW,32) bf16 c4-major
    const float* __restrict__ mask_ws,  // (2,9,HW)
    const float* __restrict__ off_ws,   // (2,72,HW)
    float* __restrict__ out)            // (4,64,9,HW)
{
    int bid = blockIdx.x;            // 8192
    int z  = bid & 7;
    int wc = (bid >> 3) & 3;
    int h  = bid >> 5;               // 0..255
    int c4 = threadIdx.x & 3;
    int pl = threadIdx.x >> 2;       // 0..63
    int w  = wc * 64 + pl;
    int pix = h * 256 + w;
    int xb = z >> 2, i = z & 3;

    const ushort_t* Tt = Tc + (size_t)z * HW * 32;

    float oxv[9], oyv[9], mv[9];
#pragma unroll
    for (int k = 0; k < 9; ++k) {
        oxv[k] = off_ws[(size_t)(z * 18 + 2 * k) * HW + pix];
        oyv[k] = off_ws[(size_t)(z * 18 + 2 * k + 1) * HW + pix];
        mv[k]  = mask_ws[(size_t)(xb * 9 + k) * HW + pix];
    }

    float* ob0 = out + ((size_t)(xb * 64 + i * 16 + c4 * 4)) * 9 * HW + pix;
    float* ob1 = ob0 + (size_t)128 * 9 * HW;
    int sec = c4 * 8;   // ushort offset of this lane's 16B sector

#pragma unroll 1
    for (int k = 0; k < 9; ++k) {
        float m = mv[k];
        float px = fminf(fmaxf((float)w + oxv[k], 0.f), 255.f);
        float py = fminf(fmaxf((float)h + oyv[k], 0.f), 255.f);
        float x0f = floorf(px), y0f = floorf(py);
        float wx = px - x0f, wy = py - y0f;
        int x0 = (int)x0f, y0 = (int)y0f;
        int x1 = min(x0 + 1, 255), y1 = min(y0 + 1, 255);

        float w00 = (1.f - wx) * (1.f - wy) * m;
        float w01 = wx * (1.f - wy) * m;
        float w10 = (1.f - wx) * wy * m;
        float w11 = wx * wy * m;

        uint4 A = *(const uint4*)(Tt + (size_t)(y0 * 256 + x0) * 32 + sec);
        uint4 B = *(const uint4*)(Tt + (size_t)(y0 * 256 + x1) * 32 + sec);
        uint4 C = *(const uint4*)(Tt + (size_t)(y1 * 256 + x0) * 32 + sec);
        uint4 D = *(const uint4*)(Tt + (size_t)(y1 * 256 + x1) * 32 + sec);

        // x,y = t0 channels 0-3 ; z,w = t1 channels 0-3 (packed bf16 pairs)
        float s0 = w00 * bflo(A.x), s1 = w00 * bfhi(A.x);
        float s2 = w00 * bflo(A.y), s3 = w00 * bfhi(A.y);
        float u0 = w00 * bflo(A.z), u1 = w00 * bfhi(A.z);
        float u2 = w00 * bflo(A.w), u3 = w00 * bfhi(A.w);

        s0 = fmaf(w01, bflo(B.x), s0); s1 = fmaf(w01, bfhi(B.x), s1);
        s2 = fmaf(w01, bflo(B.y), s2); s3 = fmaf(w01, bfhi(B.y), s3);
        u0 = fmaf(w01, bflo(B.z), u0); u1 = fmaf(w01, bfhi(B.z), u1);
        u2 = fmaf(w01, bflo(B.w), u2); u3 = fmaf(w01, bfhi(B.w), u3);

        s0 = fmaf(w10, bflo(C.x), s0); s1 = fmaf(w10, bfhi(C.x), s1);
        s2 = fmaf(w10, bflo(C.y), s2); s3 = fmaf(w10, bfhi(C.y), s3);
        u0 = fmaf(w10, bflo(C.z), u0); u1 = fmaf(w10, bfhi(C.z), u1);
        u2 = fmaf(w10, bflo(C.w), u2); u3 = fmaf(w10, bfhi(C.w), u3);

        s0 = fmaf(w11, bflo(D.x), s0); s1 = fmaf(w11, bfhi(D.x), s1);
        s2 = fmaf(w11, bflo(D.y), s2); s3 = fmaf(w11, bfhi(D.y), s3);
        u0 = fmaf(w11, bflo(D.z), u0); u1 = fmaf(w11, bfhi(D.z), u1);
        u2 = fmaf(w11, bflo(D.w), u2); u3 = fmaf(w11, bfhi(D.w), u3);

        float* p0 = ob0 + (size_t)k * HW;
        __builtin_nontemporal_store(s0, p0);
        __builtin_nontemporal_store(s1, p0 + (size_t)9 * HW);
        __builtin_nontemporal_store(s2, p0 + (size_t)18 * HW);
        __builtin_nontemporal_store(s3, p0 + (size_t)27 * HW);
        float* p1 = ob1 + (size_t)k * HW;
        __builtin_nontemporal_store(u0, p1);
        __builtin_nontemporal_store(u1, p1 + (size_t)9 * HW);
        __builtin_nontemporal_store(u2, p1 + (size_t)18 * HW);
        __builtin_nontemporal_store(u3, p1 + (size_t)27 * HW);
    }
}

// ---------------------------------------------------------------------------
// Fallback path (ws too small): LDS-weight conv to planes + direct warp.
// ---------------------------------------------------------------------------
__global__ __launch_bounds__(512) void conv_offsets_lds(
    const float* __restrict__ x, const float* __restrict__ WtP,
    const float* __restrict__ biasP,
    float* __restrict__ mask_ws, float* __restrict__ off_ws)
{
    __shared__ float wl[NFEAT * WROW + NOUT];
    int tid = threadIdx.x;
    for (int idx = tid; idx < NFEAT * WROW; idx += 512) wl[idx] = WtP[idx];
    if (tid < NOUT) wl[NFEAT * WROW + tid] = biasP[tid];
    __syncthreads();

    int gid = blockIdx.x * 512 + tid;
    int b = gid >> 16;
    int pix = gid & 65535;
    int h = pix >> 8, w = pix & 255;

    float acc[NOUT];
#pragma unroll
    for (int o = 0; o < NOUT; ++o) acc[o] = wl[NFEAT * WROW + o];

    const float* xb = x + (size_t)b * 64 * HW;
    for (int p = 0; p < 9; ++p) {
        int hh = h + p / 3 - 1;
        int ww = w + p % 3 - 1;
        bool valid = ((unsigned)hh < 256u) && ((unsigned)ww < 256u);
        int poff = hh * 256 + ww;
        for (int c = 0; c < 16; ++c) {
            float xv = valid ? xb[c * HW + poff] : 0.f;
            const float* wr = &wl[(p * 16 + c) * WROW];
#pragma unroll
            for (int o = 0; o < NOUT; ++o) acc[o] = fmaf(xv, wr[o], acc[o]);
        }
    }
    for (int c = 0; c < 48; ++c) {
        float xv = xb[(16 + c) * HW + pix];
        const float* wr = &wl[(144 + c) * WROW];
#pragma unroll
        for (int o = 0; o < NOUT; ++o) acc[o] = fmaf(xv, wr[o], acc[o]);
    }
#pragma unroll
    for (int k = 0; k < 9; ++k) mask_ws[(b * 9 + k) * HW + pix] = acc[k];
#pragma unroll
    for (int t = 0; t < 72; ++t) off_ws[(b * 72 + t) * HW + pix] = acc[9 + t];
}

__global__ __launch_bounds__(256) void warp_apply(
    const float* __restrict__ y,
    const float* __restrict__ mask_ws,
    const float* __restrict__ off_ws,
    float* __restrict__ out)
{
    int w = threadIdx.x;
    int h = blockIdx.x;
    int k = blockIdx.y;
    int z = blockIdx.z;
    int xb = z >> 2, i = z & 3;
    int pix = h * 256 + w;

    float ox = off_ws[(size_t)(z * 18 + 2 * k) * HW + pix];
    float oy = off_ws[(size_t)(z * 18 + 2 * k + 1) * HW + pix];
    float m  = mask_ws[(size_t)(xb * 9 + k) * HW + pix];

    float px = fminf(fmaxf((float)w + ox, 0.f), 255.f);
    float py = fminf(fmaxf((float)h + oy, 0.f), 255.f);
    float x0f = floorf(px), y0f = floorf(py);
    float wx = px - x0f, wy = py - y0f;
    int x0 = (int)x0f, y0 = (int)y0f;
    int x1 = min(x0 + 1, 255), y1 = min(y0 + 1, 255);

    float w00 = (1.f - wx) * (1.f - wy) * m;
    float w01 = wx * (1.f - wy) * m;
    float w10 = (1.f - wx) * wy * m;
    float w11 = wx * wy * m;

    int o00 = y0 * 256 + x0, o01 = y0 * 256 + x1;
    int o10 = y1 * 256 + x0, o11 = y1 * 256 + x1;

    const float* p1 = y + (size_t)(xb * 64 + i * 16) * HW;
    const float* p2 = y + (size_t)((xb + 2) * 64 + i * 16) * HW;
    float* out1 = out + ((size_t)(xb * 64 + i * 16) * 9 + k) * HW + pix;
    float* out2 = out + ((size_t)((xb + 2) * 64 + i * 16) * 9 + k) * HW + pix;

#pragma unroll
    for (int c = 0; c < 16; ++c) {
        const float* q = p1 + (size_t)c * HW;
        float v = w00 * q[o00] + w01 * q[o01] + w10 * q[o10] + w11 * q[o11];
        out1[(size_t)c * 9 * HW] = v;
        q = p2 + (size_t)c * HW;
        v = w00 * q[o00] + w01 * q[o01] + w10 * q[o10] + w11 * q[o11];
        out2[(size_t)c * 9 * HW] = v;
    }
}

// ---------------------------------------------------------------------------
extern "C" void kernel_launch(void* const* d_in, const int* in_sizes, int n_in,
                              void* d_out, int out_size, void* d_ws, size_t ws_size,
                              hipStream_t stream) {
    const float* x            = (const float*)d_in[0];
    const float* y            = (const float*)d_in[1];
    const float* off_pconv_w  = (const float*)d_in[2];
    const float* off_w        = (const float*)d_in[3];
    const float* off_b        = (const float*)d_in[4];
    const float* mask_pconv_w = (const float*)d_in[5];
    const float* mask_w       = (const float*)d_in[6];
    const float* mask_b       = (const float*)d_in[7];
    float* out = (float*)d_out;

    // ws: [WtP 192*84 f32 + biasP: 64KB] [mask (2,9,HW) f32: 4.7MB]
    //     [off (2,72,HW) f32: 37.7MB] [Tc (8,HW,32) bf16: 33.6MB]  ~76MB
    float* WtP     = (float*)d_ws;
    float* biasP   = WtP + NFEAT * WROW;
    float* mask_ws = (float*)((char*)d_ws + 65536);
    float* off_ws  = mask_ws + (size_t)2 * 9 * HW;
    ushort_t* Tc   = (ushort_t*)(off_ws + (size_t)2 * 72 * HW);
    size_t need = 65536 + (size_t)2 * 9 * HW * 4 + (size_t)2 * 72 * HW * 4
                + (size_t)8 * HW * 32 * 2;

    setup_weights<<<64, 256, 0, stream>>>(off_pconv_w, off_w, off_b,
                                          mask_pconv_w, mask_w, mask_b, WtP, biasP);

    if (ws_size >= need) {
        conv_px4<<<512, 256, 0, stream>>>(x, WtP, biasP, mask_ws, off_ws);
        transpose_y_c<<<2048, 256, 0, stream>>>(y, Tc);
        warp_apply_c<<<8192, 256, 0, stream>>>(Tc, mask_ws, off_ws, out);
    } else {
        conv_offsets_lds<<<256, 512, 0, stream>>>(x, WtP, biasP, mask_ws, off_ws);
        dim3 g2(256, 9, 8);
        warp_apply<<<g2, 256, 0, stream>>>(y, mask_ws, off_ws, out);
    }
}